// Round 1
// baseline (500.034 us; speedup 1.0000x reference)
//
#include <hip/hip_runtime.h>
#include <hip/hip_bf16.h>

#define B_   128
#define T_   1000
#define D_   1024
#define H_   256
#define TCROP 100

typedef __attribute__((ext_vector_type(8))) short bfrag8;   // 8 x bf16 (4 VGPRs)
typedef __attribute__((ext_vector_type(4))) float f32x4;    // MFMA accumulator

__device__ __forceinline__ unsigned short f2bf(float f) {
    union { float f; unsigned int u; } v; v.f = f;
    unsigned int u = v.u;
    u += 0x7FFFu + ((u >> 16) & 1u);   // round-to-nearest-even
    return (unsigned short)(u >> 16);
}

// ---------------------------------------------------------------------------
// Kernel 1: Wx[bt][h] = sum_d x[bt][d] * W[h][d]   (bf16 MFMA, f32 out)
// Tile: BM=128, BN=128, BK=32. 256 threads = 4 waves, each wave 64x64.
// LDS: A,B tiles as bf16, XOR-swizzled 16B chunks: chunk c at (c ^ ((row>>1)&3))
// ---------------------------------------------------------------------------
__global__ __launch_bounds__(256) void gemm_bt_kernel(
        const float* __restrict__ x, const float* __restrict__ W,
        float* __restrict__ Wx) {
    __shared__ unsigned short As[128 * 32];   // 128 rows x 32 k (bf16), 64B/row
    __shared__ unsigned short Bs[128 * 32];

    const int tid  = threadIdx.x;
    const int lane = tid & 63;
    const int wave = tid >> 6;
    const int wr   = wave >> 1;            // 0..1 (M)
    const int wc   = wave & 1;             // 0..1 (N)

    const int m0 = blockIdx.x * 128;       // row (b*T+t) tile base
    const int n0 = blockIdx.y * 128;       // col (h) tile base

    // staging: 512 chunks (128 rows x 4 chunks of 8 f32); thread does tid, tid+256
    const int r0 = tid >> 2;               // 0..63
    const int c0 = tid & 3;                // chunk within row

    f32x4 acc[4][4];
#pragma unroll
    for (int m = 0; m < 4; ++m)
#pragma unroll
        for (int n = 0; n < 4; ++n) acc[m][n] = (f32x4){0.f, 0.f, 0.f, 0.f};

    const int kg = lane >> 4;              // k-chunk for fragments
    const int rr = lane & 15;

    for (int kt = 0; kt < D_; kt += 32) {
        // ---- stage A and B (global f32 -> bf16 -> LDS, swizzled) ----
#pragma unroll
        for (int p = 0; p < 2; ++p) {
            const int row = r0 + p * 64;
            const int sc  = c0 ^ ((row >> 1) & 3);
            {
                const float* src = x + (size_t)(m0 + row) * D_ + kt + c0 * 8;
                float4 f0 = *(const float4*)(src);
                float4 f1 = *(const float4*)(src + 4);
                bfrag8 v;
                v[0] = (short)f2bf(f0.x); v[1] = (short)f2bf(f0.y);
                v[2] = (short)f2bf(f0.z); v[3] = (short)f2bf(f0.w);
                v[4] = (short)f2bf(f1.x); v[5] = (short)f2bf(f1.y);
                v[6] = (short)f2bf(f1.z); v[7] = (short)f2bf(f1.w);
                *(bfrag8*)&As[row * 32 + sc * 8] = v;
            }
            {
                const float* src = W + (size_t)(n0 + row) * D_ + kt + c0 * 8;
                float4 f0 = *(const float4*)(src);
                float4 f1 = *(const float4*)(src + 4);
                bfrag8 v;
                v[0] = (short)f2bf(f0.x); v[1] = (short)f2bf(f0.y);
                v[2] = (short)f2bf(f0.z); v[3] = (short)f2bf(f0.w);
                v[4] = (short)f2bf(f1.x); v[5] = (short)f2bf(f1.y);
                v[6] = (short)f2bf(f1.z); v[7] = (short)f2bf(f1.w);
                *(bfrag8*)&Bs[row * 32 + sc * 8] = v;
            }
        }
        __syncthreads();

        // ---- fragments + MFMA ----
        bfrag8 af[4], bf[4];
#pragma unroll
        for (int m = 0; m < 4; ++m) {
            const int row = wr * 64 + m * 16 + rr;
            af[m] = *(const bfrag8*)&As[row * 32 + (kg ^ ((row >> 1) & 3)) * 8];
        }
#pragma unroll
        for (int n = 0; n < 4; ++n) {
            const int row = wc * 64 + n * 16 + rr;
            bf[n] = *(const bfrag8*)&Bs[row * 32 + (kg ^ ((row >> 1) & 3)) * 8];
        }
#pragma unroll
        for (int m = 0; m < 4; ++m)
#pragma unroll
            for (int n = 0; n < 4; ++n)
                acc[m][n] = __builtin_amdgcn_mfma_f32_16x16x32_bf16(
                    af[m], bf[n], acc[m][n], 0, 0, 0);
        __syncthreads();
    }

    // ---- epilogue: C[row=(lane>>4)*4+j][col=lane&15] per 16x16 frag ----
    const int cl = lane & 15;
    const int rg = lane >> 4;
#pragma unroll
    for (int m = 0; m < 4; ++m) {
#pragma unroll
        for (int n = 0; n < 4; ++n) {
#pragma unroll
            for (int j = 0; j < 4; ++j) {
                const int row = m0 + wr * 64 + m * 16 + rg * 4 + j;
                const int col = n0 + wc * 64 + n * 16 + cl;
                Wx[(size_t)row * H_ + col] = acc[m][n][j];
            }
        }
    }
}

// ---------------------------------------------------------------------------
// Kernel 2: sequential scan over t. One wave per b; lane owns h = 4*lane..+3.
// ut = a*ut + (1-a)*wx ; for t>=100: out += exp(ut)/sum_h(exp(ut))
// (max-subtraction skipped: |ut| <= ~2, exp cannot overflow)
// ---------------------------------------------------------------------------
__global__ __launch_bounds__(64) void scan_kernel(
        const float* __restrict__ Wx, const float* __restrict__ alpha,
        float* __restrict__ out) {
    const int b    = blockIdx.x;
    const int lane = threadIdx.x;

    const float AMIN = 0.81873075307798182f;   // exp(-1/5)
    const float AMAX = 0.96078943915232320f;   // exp(-1/25)

    float4 al = *(const float4*)(alpha + lane * 4);
    float a[4], om[4];
    a[0] = fminf(fmaxf(al.x, AMIN), AMAX);
    a[1] = fminf(fmaxf(al.y, AMIN), AMAX);
    a[2] = fminf(fmaxf(al.z, AMIN), AMAX);
    a[3] = fminf(fmaxf(al.w, AMIN), AMAX);
    om[0] = 1.0f - a[0]; om[1] = 1.0f - a[1];
    om[2] = 1.0f - a[2]; om[3] = 1.0f - a[3];

    float ut[4]  = {0.f, 0.f, 0.f, 0.f};
    float acc[4] = {0.f, 0.f, 0.f, 0.f};

    const float* base = Wx + (size_t)b * T_ * H_ + lane * 4;

    // t < TCROP: EMA only, no accumulation
#pragma unroll 4
    for (int t = 0; t < TCROP; ++t) {
        float4 wx = *(const float4*)(base + (size_t)t * H_);
        ut[0] = a[0] * ut[0] + om[0] * wx.x;
        ut[1] = a[1] * ut[1] + om[1] * wx.y;
        ut[2] = a[2] * ut[2] + om[2] * wx.z;
        ut[3] = a[3] * ut[3] + om[3] * wx.w;
    }

#pragma unroll 4
    for (int t = TCROP; t < T_; ++t) {
        float4 wx = *(const float4*)(base + (size_t)t * H_);
        ut[0] = a[0] * ut[0] + om[0] * wx.x;
        ut[1] = a[1] * ut[1] + om[1] * wx.y;
        ut[2] = a[2] * ut[2] + om[2] * wx.z;
        ut[3] = a[3] * ut[3] + om[3] * wx.w;

        float e0 = __expf(ut[0]);
        float e1 = __expf(ut[1]);
        float e2 = __expf(ut[2]);
        float e3 = __expf(ut[3]);
        float s = (e0 + e1) + (e2 + e3);
        s += __shfl_xor(s, 1);
        s += __shfl_xor(s, 2);
        s += __shfl_xor(s, 4);
        s += __shfl_xor(s, 8);
        s += __shfl_xor(s, 16);
        s += __shfl_xor(s, 32);
        const float r = 1.0f / s;
        acc[0] += e0 * r;
        acc[1] += e1 * r;
        acc[2] += e2 * r;
        acc[3] += e3 * r;
    }

    float4 o;
    o.x = acc[0]; o.y = acc[1]; o.z = acc[2]; o.w = acc[3];
    *(float4*)(out + (size_t)b * H_ + lane * 4) = o;
}

extern "C" void kernel_launch(void* const* d_in, const int* in_sizes, int n_in,
                              void* d_out, int out_size, void* d_ws, size_t ws_size,
                              hipStream_t stream) {
    const float* x     = (const float*)d_in[0];   // [B,T,D]
    const float* W     = (const float*)d_in[1];   // [H,D]
    const float* alpha = (const float*)d_in[2];   // [H]
    float* out = (float*)d_out;                   // [B,H]
    float* Wx  = (float*)d_ws;                    // [B*T, H] f32 = 131 MB

    dim3 ggrid((B_ * T_) / 128, H_ / 128);        // (1000, 2)
    gemm_bt_kernel<<<ggrid, 256, 0, stream>>>(x, W, Wx);
    scan_kernel<<<B_, 64, 0, stream>>>(Wx, alpha, out);
}

// Round 2
// 175.118 us; speedup vs baseline: 2.8554x; 2.8554x over previous
//
#include <hip/hip_runtime.h>
#include <hip/hip_bf16.h>

#define B_    128
#define T_    1000
#define D_    1024
#define H_    256
#define TCROP 100
#define CHUNK 50
#define NCH   20        // T_/CHUNK
#define CSKIP (TCROP/CHUNK)   // chunks with no output contribution

typedef __attribute__((ext_vector_type(8))) short bfrag8;   // 8 x bf16
typedef __attribute__((ext_vector_type(4))) float f32x4;

__device__ __forceinline__ unsigned short f2bf(float f) {
    union { float f; unsigned int u; } v; v.f = f;
    unsigned int u = v.u;
    u += 0x7FFFu + ((u >> 16) & 1u);   // RNE
    return (unsigned short)(u >> 16);
}
__device__ __forceinline__ float bf2f(unsigned short u) {
    union { unsigned int u; float f; } v; v.u = ((unsigned int)u) << 16;
    return v.f;
}

// ---------------------------------------------------------------------------
// Kernel 0: W f32 [H][D] -> bf16 [H][D] (plain row-major)
// ---------------------------------------------------------------------------
__global__ __launch_bounds__(256) void wconv_kernel(
        const float* __restrict__ W, unsigned short* __restrict__ Wbf) {
    const int i = (blockIdx.x * 256 + threadIdx.x) * 8;   // 128 blocks cover 256*1024
    float4 f0 = *(const float4*)(W + i);
    float4 f1 = *(const float4*)(W + i + 4);
    bfrag8 v;
    v[0] = (short)f2bf(f0.x); v[1] = (short)f2bf(f0.y);
    v[2] = (short)f2bf(f0.z); v[3] = (short)f2bf(f0.w);
    v[4] = (short)f2bf(f1.x); v[5] = (short)f2bf(f1.y);
    v[6] = (short)f2bf(f1.z); v[7] = (short)f2bf(f1.w);
    *(bfrag8*)(Wbf + i) = v;
}

// ---------------------------------------------------------------------------
// Kernel 1: Wx[bt][h] = sum_d x[bt][d]*W[h][d], bf16 MFMA, bf16 out.
// BM=128, BN=256(all of H), BK=64. 512 thr = 8 waves (2M x 4N), wave = 64x64.
// LDS 48 KB single-buffer. 16B-chunk XOR swizzle: chunk j of row r at j^(r&7).
// B staged via global_load_lds (source pre-swizzled); A reg-staged f32->bf16
// with write-side swizzle.
// ---------------------------------------------------------------------------
__global__ __launch_bounds__(512) void gemm_kernel(
        const float* __restrict__ x, const unsigned short* __restrict__ Wbf,
        unsigned short* __restrict__ Wx) {
    __shared__ unsigned short As[128 * 64];   // 16 KB  [128][64] bf16
    __shared__ unsigned short Bs[256 * 64];   // 32 KB  [256][64] bf16

    const int tid  = threadIdx.x;
    const int lane = tid & 63;
    const int wave = tid >> 6;
    const int wr   = wave >> 2;          // 0..1
    const int wc   = wave & 3;           // 0..3
    const int m0   = blockIdx.x * 128;

    f32x4 acc[4][4];
#pragma unroll
    for (int m = 0; m < 4; ++m)
#pragma unroll
        for (int n = 0; n < 4; ++n) acc[m][n] = (f32x4){0.f, 0.f, 0.f, 0.f};

    const int rr  = lane & 15;
    const int kh  = lane >> 4;           // 0..3
    const int ra0 = tid >> 3;            // A-stage row (q adds 64)
    const int ja  = tid & 7;             // A-stage chunk

    for (int kt = 0; kt < D_; kt += 64) {
        // ---- B stage: 4x global_load_lds, 16B/lane, linear dest ----
#pragma unroll
        for (int q = 0; q < 4; ++q) {
            const int li = q * 512 + tid;        // 0..2047
            const int r  = li >> 3;
            const int j  = li & 7;
            const int jj = j ^ (r & 7);          // pre-swizzled source
            const unsigned short* src = Wbf + (size_t)r * D_ + kt + jj * 8;
            unsigned short* dst = &Bs[li * 8];
            __builtin_amdgcn_global_load_lds(
                (const __attribute__((address_space(1))) void*)src,
                (__attribute__((address_space(3))) void*)dst, 16, 0, 0);
        }
        // ---- A stage: reg path, f32->bf16, write-side swizzle ----
#pragma unroll
        for (int q = 0; q < 2; ++q) {
            const int r = ra0 + q * 64;
            const float* src = x + (size_t)(m0 + r) * D_ + kt + ja * 8;
            float4 f0 = *(const float4*)src;
            float4 f1 = *(const float4*)(src + 4);
            bfrag8 v;
            v[0] = (short)f2bf(f0.x); v[1] = (short)f2bf(f0.y);
            v[2] = (short)f2bf(f0.z); v[3] = (short)f2bf(f0.w);
            v[4] = (short)f2bf(f1.x); v[5] = (short)f2bf(f1.y);
            v[6] = (short)f2bf(f1.z); v[7] = (short)f2bf(f1.w);
            *(bfrag8*)&As[r * 64 + ((ja ^ (r & 7)) * 8)] = v;
        }
        __syncthreads();

        // ---- fragments + MFMA (split kk to cap VGPRs) ----
#pragma unroll
        for (int kk = 0; kk < 2; ++kk) {
            const int c16 = kk * 4 + kh;
            bfrag8 af[4], bfr[4];
#pragma unroll
            for (int m = 0; m < 4; ++m) {
                const int row = wr * 64 + m * 16 + rr;
                af[m] = *(const bfrag8*)&As[row * 64 + ((c16 ^ (row & 7)) * 8)];
            }
#pragma unroll
            for (int n = 0; n < 4; ++n) {
                const int row = wc * 64 + n * 16 + rr;
                bfr[n] = *(const bfrag8*)&Bs[row * 64 + ((c16 ^ (row & 7)) * 8)];
            }
#pragma unroll
            for (int m = 0; m < 4; ++m)
#pragma unroll
                for (int n = 0; n < 4; ++n)
                    acc[m][n] = __builtin_amdgcn_mfma_f32_16x16x32_bf16(
                        af[m], bfr[n], acc[m][n], 0, 0, 0);
        }
        __syncthreads();
    }

    // ---- epilogue: bf16 store. C[row=(lane>>4)*4+j][col=lane&15] ----
    const int cl = lane & 15, rg = lane >> 4;
#pragma unroll
    for (int m = 0; m < 4; ++m)
#pragma unroll
        for (int n = 0; n < 4; ++n)
#pragma unroll
            for (int j = 0; j < 4; ++j) {
                const int row = m0 + wr * 64 + m * 16 + rg * 4 + j;
                const int col = wc * 64 + n * 16 + cl;
                Wx[(size_t)row * H_ + col] = f2bf(acc[m][n][j]);
            }
}

// ---------------------------------------------------------------------------
// Scan decomposition: ut is a linear recurrence -> chunk it.
// Phase A: per (b, chunk) local EMA final value F (zero init).
// Phase B: carry prefix S_c = ut at chunk start (S_0=0; S_{c+1}=a^L*S_c+F_c).
// Phase C: re-run exact recurrence seeded with S_c + softmax accumulation.
// Phase D: reduce chunk partials.
// ---------------------------------------------------------------------------
__global__ __launch_bounds__(64) void scanA_kernel(
        const unsigned short* __restrict__ Wx, const float* __restrict__ alpha,
        float* __restrict__ F) {
    const int c = blockIdx.x, b = blockIdx.y;
    const int lane = threadIdx.x;
    const int h = lane * 4;

    const float AMIN = 0.81873075307798182f, AMAX = 0.96078943915232320f;
    float4 al = *(const float4*)(alpha + h);
    float a[4]  = {fminf(fmaxf(al.x, AMIN), AMAX), fminf(fmaxf(al.y, AMIN), AMAX),
                   fminf(fmaxf(al.z, AMIN), AMAX), fminf(fmaxf(al.w, AMIN), AMAX)};
    float om[4] = {1.f - a[0], 1.f - a[1], 1.f - a[2], 1.f - a[3]};

    float ut[4] = {0.f, 0.f, 0.f, 0.f};
    const unsigned short* base = Wx + ((size_t)b * T_ + c * CHUNK) * H_ + h;
#pragma unroll 5
    for (int t = 0; t < CHUNK; ++t) {
        unsigned long long wv = *(const unsigned long long*)(base + (size_t)t * H_);
        ut[0] = a[0] * ut[0] + om[0] * bf2f((unsigned short)wv);
        ut[1] = a[1] * ut[1] + om[1] * bf2f((unsigned short)(wv >> 16));
        ut[2] = a[2] * ut[2] + om[2] * bf2f((unsigned short)(wv >> 32));
        ut[3] = a[3] * ut[3] + om[3] * bf2f((unsigned short)(wv >> 48));
    }
    float4 o; o.x = ut[0]; o.y = ut[1]; o.z = ut[2]; o.w = ut[3];
    *(float4*)(F + ((size_t)b * NCH + c) * H_ + h) = o;
}

__global__ __launch_bounds__(256) void scanB_kernel(
        const float* __restrict__ F, const float* __restrict__ alpha,
        float* __restrict__ S) {
    const int b = blockIdx.x, h = threadIdx.x;
    const float AMIN = 0.81873075307798182f, AMAX = 0.96078943915232320f;
    const float a = fminf(fmaxf(alpha[h], AMIN), AMAX);
    const float aL = powf(a, (float)CHUNK);
    float s = 0.f;
    for (int c = 0; c < NCH; ++c) {
        S[((size_t)b * NCH + c) * H_ + h] = s;
        s = aL * s + F[((size_t)b * NCH + c) * H_ + h];
    }
}

__global__ __launch_bounds__(64) void scanC_kernel(
        const unsigned short* __restrict__ Wx, const float* __restrict__ alpha,
        const float* __restrict__ S, float* __restrict__ P) {
    const int c = blockIdx.x + CSKIP;     // 2..19
    const int b = blockIdx.y;
    const int lane = threadIdx.x;
    const int h = lane * 4;

    const float AMIN = 0.81873075307798182f, AMAX = 0.96078943915232320f;
    float4 al = *(const float4*)(alpha + h);
    float a[4]  = {fminf(fmaxf(al.x, AMIN), AMAX), fminf(fmaxf(al.y, AMIN), AMAX),
                   fminf(fmaxf(al.z, AMIN), AMAX), fminf(fmaxf(al.w, AMIN), AMAX)};
    float om[4] = {1.f - a[0], 1.f - a[1], 1.f - a[2], 1.f - a[3]};

    float4 s0 = *(const float4*)(S + ((size_t)b * NCH + c) * H_ + h);
    float ut[4]  = {s0.x, s0.y, s0.z, s0.w};
    float acc[4] = {0.f, 0.f, 0.f, 0.f};

    const unsigned short* base = Wx + ((size_t)b * T_ + c * CHUNK) * H_ + h;
#pragma unroll 5
    for (int t = 0; t < CHUNK; ++t) {
        unsigned long long wv = *(const unsigned long long*)(base + (size_t)t * H_);
        ut[0] = a[0] * ut[0] + om[0] * bf2f((unsigned short)wv);
        ut[1] = a[1] * ut[1] + om[1] * bf2f((unsigned short)(wv >> 16));
        ut[2] = a[2] * ut[2] + om[2] * bf2f((unsigned short)(wv >> 32));
        ut[3] = a[3] * ut[3] + om[3] * bf2f((unsigned short)(wv >> 48));

        float e0 = __expf(ut[0]);   // |ut| <= max|wx| ~ 3.5: no overflow, skip max-sub
        float e1 = __expf(ut[1]);
        float e2 = __expf(ut[2]);
        float e3 = __expf(ut[3]);
        float s = (e0 + e1) + (e2 + e3);
        s += __shfl_xor(s, 1);
        s += __shfl_xor(s, 2);
        s += __shfl_xor(s, 4);
        s += __shfl_xor(s, 8);
        s += __shfl_xor(s, 16);
        s += __shfl_xor(s, 32);
        const float r = 1.0f / s;
        acc[0] += e0 * r; acc[1] += e1 * r; acc[2] += e2 * r; acc[3] += e3 * r;
    }
    float4 o; o.x = acc[0]; o.y = acc[1]; o.z = acc[2]; o.w = acc[3];
    *(float4*)(P + ((size_t)b * NCH + c) * H_ + h) = o;
}

__global__ __launch_bounds__(256) void scanD_kernel(
        const float* __restrict__ P, float* __restrict__ out) {
    const int b = blockIdx.x, h = threadIdx.x;
    float s = 0.f;
    for (int c = CSKIP; c < NCH; ++c) s += P[((size_t)b * NCH + c) * H_ + h];
    out[(size_t)b * H_ + h] = s;
}

extern "C" void kernel_launch(void* const* d_in, const int* in_sizes, int n_in,
                              void* d_out, int out_size, void* d_ws, size_t ws_size,
                              hipStream_t stream) {
    const float* x     = (const float*)d_in[0];   // [B,T,D]
    const float* W     = (const float*)d_in[1];   // [H,D]
    const float* alpha = (const float*)d_in[2];   // [H]
    float* out = (float*)d_out;                   // [B,H]

    char* ws = (char*)d_ws;
    unsigned short* Wbf = (unsigned short*)ws;                    // 512 KB
    unsigned short* Wx  = (unsigned short*)(ws + (1 << 20));      // 65.5 MB
    float* F = (float*)(ws + (size_t)68 * (1 << 20));             // 2.62 MB
    float* S = (float*)(ws + (size_t)72 * (1 << 20));             // 2.62 MB
    float* P = (float*)(ws + (size_t)76 * (1 << 20));             // 2.62 MB

    wconv_kernel<<<128, 256, 0, stream>>>(W, Wbf);
    gemm_kernel<<<(B_ * T_) / 128, 512, 0, stream>>>(x, Wbf, Wx);
    scanA_kernel<<<dim3(NCH, B_), 64, 0, stream>>>(Wx, alpha, F);
    scanB_kernel<<<B_, H_, 0, stream>>>(F, alpha, S);
    scanC_kernel<<<dim3(NCH - CSKIP, B_), 64, 0, stream>>>(Wx, alpha, S, P);
    scanD_kernel<<<B_, H_, 0, stream>>>(P, out);
}